// Round 1
// baseline (824.790 us; speedup 1.0000x reference)
//
#include <hip/hip_runtime.h>
#include <hip/hip_bf16.h>
#include <stdint.h>

typedef __bf16 bf16_t;
typedef __bf16 bf16x8 __attribute__((ext_vector_type(8)));
typedef float f32x4 __attribute__((ext_vector_type(4)));
typedef float floatv4 __attribute__((ext_vector_type(4)));

static __device__ __forceinline__ float bflo(unsigned int p){ return __uint_as_float(p << 16); }
static __device__ __forceinline__ float bfhi(unsigned int p){ return __uint_as_float(p & 0xffff0000u); }

constexpr int NN = 100000;
constexpr int NE = 1600000;

// ---------------- prep kernels ----------------

__global__ void k_init(float* deg, int* cnt, int* fill, int n){
  int i = blockIdx.x*256 + threadIdx.x;
  if (i < n){ deg[i] = 0.f; cnt[i] = 0; fill[i] = 0; }
}

__global__ void k_deg(const int* __restrict__ row, const float* __restrict__ w,
                      float* __restrict__ deg, int* __restrict__ cnt, int e){
  int i = blockIdx.x*256 + threadIdx.x;
  if (i < e){ int r = row[i]; atomicAdd(&deg[r], w[i]); atomicAdd(&cnt[r], 1); }
}

__global__ void k_dinv(const float* __restrict__ deg, float* __restrict__ dinv, int n){
  int i = blockIdx.x*256 + threadIdx.x;
  if (i < n){ float d = deg[i]; dinv[i] = (d > 0.f) ? rsqrtf(d) : 0.f; }
}

__global__ void k_scan1(const int* __restrict__ cnt, int* __restrict__ tmp,
                        int* __restrict__ bsum, int n){
  __shared__ int s[256];
  int i = blockIdx.x*256 + threadIdx.x;
  s[threadIdx.x] = (i < n) ? cnt[i] : 0;
  __syncthreads();
  for (int off = 1; off < 256; off <<= 1){
    int t = (threadIdx.x >= off) ? s[threadIdx.x - off] : 0;
    __syncthreads();
    s[threadIdx.x] += t;
    __syncthreads();
  }
  if (i < n) tmp[i] = s[threadIdx.x];
  if (threadIdx.x == 255) bsum[blockIdx.x] = s[255];
}

__global__ void k_scan2(int* bsum, int nb){
  if (threadIdx.x == 0 && blockIdx.x == 0){
    int run = 0;
    for (int b = 0; b < nb; ++b){ int t = bsum[b]; bsum[b] = run; run += t; }
  }
}

__global__ void k_scan3(const int* __restrict__ tmp, const int* __restrict__ bsum,
                        int* __restrict__ rowptr, int n){
  int i = blockIdx.x*256 + threadIdx.x;
  if (i < n) rowptr[i+1] = tmp[i] + bsum[blockIdx.x];
  if (i == 0) rowptr[0] = 0;
}

__global__ void k_fill(const int* __restrict__ row, const int* __restrict__ col,
                       const float* __restrict__ w, const float* __restrict__ dinv,
                       const int* __restrict__ rowptr, int* __restrict__ fill,
                       int* __restrict__ acol, float* __restrict__ aw, int e){
  int i = blockIdx.x*256 + threadIdx.x;
  if (i < e){
    int r = row[i], c = col[i];
    int pos = rowptr[r] + atomicAdd(&fill[r], 1);
    acol[pos] = c;
    aw[pos] = -(dinv[r] * w[i] * dinv[c]);   // store -wn: Lx is a plain weighted gather-sum
  }
}

// transpose (nc,128,128) f32 -> (nc,128,128) bf16 with [chunk][col][k] layout
__global__ void k_transw(const float* __restrict__ in, bf16_t* __restrict__ out, int total){
  int idx = blockIdx.x*256 + threadIdx.x;
  if (idx < total){
    int c = idx >> 14, r = (idx >> 7) & 127, j = idx & 127;
    out[(c << 14) + (j << 7) + r] = (bf16_t)in[idx];
  }
}

// ---------------- GEMM: OUT(Mx128) = relu?( [A0|A1|A2] @ Wt^T + bias ) ----------------
// Wt layout: (NCHUNK,128,128) = [chunk][col][k], bf16. A chunks each K=128 (row stride astride).
// 128x128 block tile, 4 waves in 2x2, each wave 64x64 via 4x4 frags of 16x16x32.
template<bool SRCF32, int NCHUNK>
__global__ __launch_bounds__(256) void k_gemm(
    const void* __restrict__ a0, const void* __restrict__ a1, const void* __restrict__ a2,
    int astride,
    const bf16_t* __restrict__ Wt, const float* __restrict__ bias,
    bf16_t* __restrict__ out, int M, int dorelu)
{
  __shared__ bf16_t As[128][40];   // 32 k + 8 pad -> 80B row stride, conflict-light b128 reads
  const int tid = threadIdx.x;
  const int wave = tid >> 6, lane = tid & 63;
  const int wm = wave >> 1, wn = wave & 1;
  const int l15 = lane & 15, lq = lane >> 4;
  const int blockRow = blockIdx.x * 128;

  f32x4 acc[4][4];
  #pragma unroll
  for (int a = 0; a < 4; ++a)
    #pragma unroll
    for (int b = 0; b < 4; ++b) acc[a][b] = f32x4{0.f,0.f,0.f,0.f};

  const int srow = tid >> 1;            // staging row 0..127
  const int scol = (tid & 1) * 16;      // staging col 0 or 16
  const int grow = blockRow + srow;

  #pragma unroll
  for (int chunk = 0; chunk < NCHUNK; ++chunk){
    const void* src = (chunk == 0) ? a0 : ((chunk == 1) ? a1 : a2);
    #pragma unroll
    for (int k4 = 0; k4 < 4; ++k4){
      const int kk = k4 * 32;
      // ---- stage A tile 128x32 (convert f32->bf16 on the fly for GEMM1) ----
      {
        union { bf16_t h[16]; uint4 q[2]; } u;
        if (grow < M){
          if (SRCF32){
            const float* p = (const float*)src + (size_t)grow*astride + kk + scol;
            floatv4 vv[4];
            #pragma unroll
            for (int j = 0; j < 4; ++j) vv[j] = *(const floatv4*)(p + j*4);
            #pragma unroll
            for (int j = 0; j < 16; ++j) u.h[j] = (bf16_t)vv[j>>2][j&3];
          } else {
            const bf16_t* p = (const bf16_t*)src + (size_t)grow*astride + kk + scol;
            u.q[0] = *(const uint4*)p;
            u.q[1] = *(const uint4*)(p + 8);
          }
        } else {
          u.q[0] = make_uint4(0,0,0,0);
          u.q[1] = make_uint4(0,0,0,0);
        }
        *(uint4*)&As[srow][scol]     = u.q[0];
        *(uint4*)&As[srow][scol + 8] = u.q[1];
      }
      __syncthreads();
      // ---- fragments + MFMA ----
      bf16x8 af[4], bfr[4];
      #pragma unroll
      for (int fm = 0; fm < 4; ++fm)
        af[fm] = *(const bf16x8*)&As[wm*64 + fm*16 + l15][lq*8];
      #pragma unroll
      for (int fn = 0; fn < 4; ++fn){
        int colg = wn*64 + fn*16 + l15;
        bfr[fn] = *(const bf16x8*)&Wt[((size_t)((chunk << 7) + colg) << 7) + kk + lq*8];
      }
      #pragma unroll
      for (int fm = 0; fm < 4; ++fm)
        #pragma unroll
        for (int fn = 0; fn < 4; ++fn)
          acc[fm][fn] = __builtin_amdgcn_mfma_f32_16x16x32_bf16(af[fm], bfr[fn], acc[fm][fn], 0, 0, 0);
      __syncthreads();
    }
  }
  // ---- epilogue: bias + relu + bf16 store ----
  #pragma unroll
  for (int fm = 0; fm < 4; ++fm){
    #pragma unroll
    for (int j = 0; j < 4; ++j){
      int r = wm*64 + fm*16 + lq*4 + j;
      int growo = blockRow + r;
      if (growo < M){
        #pragma unroll
        for (int fn = 0; fn < 4; ++fn){
          int c = wn*64 + fn*16 + l15;
          float v = acc[fm][fn][j] + bias[c];
          if (dorelu) v = fmaxf(v, 0.f);
          out[((size_t)growo << 7) + c] = (bf16_t)v;
        }
      }
    }
  }
}

// ---------------- SpMM: out[i] = alpha * sum_e aw[e]*V[col[e]]  (- sub[i]) ----------------
// one wave per node; lane owns 2 packed bf16 features (4B coalesced gathers, 256B/edge/wave)
__global__ __launch_bounds__(256) void k_spmm(
    const int* __restrict__ rowptr, const int* __restrict__ acol, const float* __restrict__ aw,
    const bf16_t* __restrict__ V, const bf16_t* __restrict__ sub, float alpha,
    bf16_t* __restrict__ out, int n)
{
  int node = blockIdx.x*4 + (threadIdx.x >> 6);
  if (node >= n) return;
  int lane = threadIdx.x & 63;
  int fo = lane * 2;
  int e = rowptr[node], e1 = rowptr[node+1];
  float acc0 = 0.f, acc1 = 0.f;
  for (; e + 2 <= e1; e += 2){
    int c0 = acol[e], c1 = acol[e+1];
    float w0 = aw[e], w1 = aw[e+1];
    unsigned int p0 = *(const unsigned int*)(V + ((size_t)c0 << 7) + fo);
    unsigned int p1 = *(const unsigned int*)(V + ((size_t)c1 << 7) + fo);
    acc0 += w0 * bflo(p0); acc1 += w0 * bfhi(p0);
    acc0 += w1 * bflo(p1); acc1 += w1 * bfhi(p1);
  }
  if (e < e1){
    int c0 = acol[e]; float w0 = aw[e];
    unsigned int p0 = *(const unsigned int*)(V + ((size_t)c0 << 7) + fo);
    acc0 += w0 * bflo(p0); acc1 += w0 * bfhi(p0);
  }
  float r0 = alpha * acc0, r1 = alpha * acc1;
  if (sub){
    unsigned int s = *(const unsigned int*)(sub + ((size_t)node << 7) + fo);
    r0 -= bflo(s); r1 -= bfhi(s);
  }
  union { bf16_t h[2]; unsigned int u; } o;
  o.h[0] = (bf16_t)r0; o.h[1] = (bf16_t)r1;
  *(unsigned int*)(out + ((size_t)node << 7) + fo) = o.u;
}

// ---------------- head: logits = h@W2 + b2 ; softmax over 2 classes ----------------
__global__ __launch_bounds__(256) void k_head(
    const bf16_t* __restrict__ h, const float* __restrict__ W2, const float* __restrict__ b2,
    float* __restrict__ out, int n)
{
  int node = blockIdx.x*4 + (threadIdx.x >> 6);
  if (node >= n) return;
  int lane = threadIdx.x & 63;
  unsigned int p = *(const unsigned int*)(h + ((size_t)node << 7) + lane*2);
  float h0 = bflo(p), h1 = bfhi(p);
  floatv4 w = *(const floatv4*)(W2 + lane*4);   // [f][0],[f][1],[f+1][0],[f+1][1]
  float p0 = h0*w[0] + h1*w[2];
  float p1 = h0*w[1] + h1*w[3];
  #pragma unroll
  for (int s = 32; s > 0; s >>= 1){
    p0 += __shfl_xor(p0, s, 64);
    p1 += __shfl_xor(p1, s, 64);
  }
  if (lane == 0){
    float l0 = p0 + b2[0], l1 = p1 + b2[1];
    float m = fmaxf(l0, l1);
    float e0 = __expf(l0 - m), e1 = __expf(l1 - m);
    float inv = 1.f / (e0 + e1);
    out[(size_t)node*2]     = e0 * inv;
    out[(size_t)node*2 + 1] = e1 * inv;
  }
}

// ---------------- launch ----------------

extern "C" void kernel_launch(void* const* d_in, const int* in_sizes, int n_in,
                              void* d_out, int out_size, void* d_ws, size_t ws_size,
                              hipStream_t stream)
{
  const float* x   = (const float*)d_in[0];
  const int*   ei  = (const int*)d_in[1];
  const float* ew  = (const float*)d_in[2];
  const float* W1  = (const float*)d_in[3];
  const float* b1  = (const float*)d_in[4];
  const float* c1W = (const float*)d_in[5];
  const float* c1b = (const float*)d_in[6];
  const float* c2W = (const float*)d_in[7];
  const float* c2b = (const float*)d_in[8];
  const float* W2  = (const float*)d_in[9];
  const float* b2  = (const float*)d_in[10];
  float* out = (float*)d_out;

  const int n = NN, e = NE;
  const int* row = ei;
  const int* col = ei + e;

  char* ws = (char*)d_ws;
  size_t off = 0;
  auto carve = [&](size_t bytes)->void*{
    void* p = ws + off;
    off += (bytes + 255) & ~(size_t)255;
    return p;
  };
  bf16_t* A    = (bf16_t*)carve((size_t)n*128*2);
  bf16_t* B    = (bf16_t*)carve((size_t)n*128*2);
  bf16_t* C    = (bf16_t*)carve((size_t)n*128*2);
  bf16_t* D    = (bf16_t*)carve((size_t)n*128*2);
  float*  deg  = (float*)carve((size_t)n*4);
  float*  dinv = (float*)carve((size_t)n*4);
  int*    cnt  = (int*)carve((size_t)n*4);
  int*    fill = (int*)carve((size_t)n*4);
  int*    tmp  = (int*)carve((size_t)n*4);
  int*    rowptr = (int*)carve((size_t)(n+1)*4);
  int*    bsum = (int*)carve(512*4);
  int*    acol = (int*)carve((size_t)e*4);
  float*  aw   = (float*)carve((size_t)e*4);
  bf16_t* Wt1  = (bf16_t*)carve(2*128*128*2);
  bf16_t* Wtc1 = (bf16_t*)carve(3*128*128*2);
  bf16_t* Wtc2 = (bf16_t*)carve(3*128*128*2);
  (void)ws_size; (void)in_sizes; (void)n_in; (void)out_size;

  const int NB_N = (n + 255)/256;   // 391
  const int NB_E = (e + 255)/256;   // 6250
  const int NB_G = (n + 127)/128;   // 782
  const int NB_W = (n + 3)/4;       // 25000

  k_init<<<NB_N,256,0,stream>>>(deg, cnt, fill, n);
  k_deg <<<NB_E,256,0,stream>>>(row, ew, deg, cnt, e);
  k_dinv<<<NB_N,256,0,stream>>>(deg, dinv, n);
  k_scan1<<<NB_N,256,0,stream>>>(cnt, tmp, bsum, n);
  k_scan2<<<1,64,0,stream>>>(bsum, NB_N);
  k_scan3<<<NB_N,256,0,stream>>>(tmp, bsum, rowptr, n);
  k_fill<<<NB_E,256,0,stream>>>(row, col, ew, dinv, rowptr, fill, acol, aw, e);
  k_transw<<<(2*16384+255)/256,256,0,stream>>>(W1,  Wt1,  2*16384);
  k_transw<<<(3*16384+255)/256,256,0,stream>>>(c1W, Wtc1, 3*16384);
  k_transw<<<(3*16384+255)/256,256,0,stream>>>(c2W, Wtc2, 3*16384);

  // h0 = relu(x @ W1 + b1)        -> A
  k_gemm<true,2><<<NB_G,256,0,stream>>>(x, x+128, nullptr, 256, Wt1, b1, A, n, 1);
  // conv1: Tx1 = Lx(h0)           -> B
  k_spmm<<<NB_W,256,0,stream>>>(rowptr, acol, aw, A, nullptr, 1.f, B, n);
  //        Tx2 = 2*Lx(Tx1) - h0   -> C
  k_spmm<<<NB_W,256,0,stream>>>(rowptr, acol, aw, B, A, 2.f, C, n);
  //        h1 = relu([A|B|C] @ Wc1 + b) -> D
  k_gemm<false,3><<<NB_G,256,0,stream>>>(A, B, C, 128, Wtc1, c1b, D, n, 1);
  // conv2
  k_spmm<<<NB_W,256,0,stream>>>(rowptr, acol, aw, D, nullptr, 1.f, B, n);
  k_spmm<<<NB_W,256,0,stream>>>(rowptr, acol, aw, B, D, 2.f, C, n);
  k_gemm<false,3><<<NB_G,256,0,stream>>>(D, B, C, 128, Wtc2, c2b, A, n, 1);
  // head
  k_head<<<NB_W,256,0,stream>>>(A, W2, b2, out, n);
}

// Round 2
// 613.059 us; speedup vs baseline: 1.3454x; 1.3454x over previous
//
#include <hip/hip_runtime.h>
#include <hip/hip_bf16.h>
#include <stdint.h>

typedef __bf16 bf16_t;
typedef __bf16 bf16x8 __attribute__((ext_vector_type(8)));
typedef float f32x4 __attribute__((ext_vector_type(4)));
typedef float floatv4 __attribute__((ext_vector_type(4)));

static __device__ __forceinline__ float bflo(unsigned int p){ return __uint_as_float(p << 16); }
static __device__ __forceinline__ float bfhi(unsigned int p){ return __uint_as_float(p & 0xffff0000u); }

constexpr int NN = 100000;
constexpr int NE = 1600000;

// ---------------- CSR build ----------------
// one device-scope atomic per edge: rank-within-row + histogram in one op
__global__ void k_count(const int* __restrict__ row, int* __restrict__ cnt,
                        int* __restrict__ pos, int e){
  int i = blockIdx.x*256 + threadIdx.x;
  if (i < e) pos[i] = atomicAdd(&cnt[row[i]], 1);
}

__global__ void k_scan1(const int* __restrict__ cnt, int* __restrict__ tmp,
                        int* __restrict__ bsum, int n){
  __shared__ int s[256];
  int i = blockIdx.x*256 + threadIdx.x;
  s[threadIdx.x] = (i < n) ? cnt[i] : 0;
  __syncthreads();
  for (int off = 1; off < 256; off <<= 1){
    int t = (threadIdx.x >= off) ? s[threadIdx.x - off] : 0;
    __syncthreads();
    s[threadIdx.x] += t;
    __syncthreads();
  }
  if (i < n) tmp[i] = s[threadIdx.x];
  if (threadIdx.x == 255) bsum[blockIdx.x] = s[255];
}

__global__ void k_scan2(int* bsum, int nb){
  if (threadIdx.x == 0 && blockIdx.x == 0){
    int run = 0;
    for (int b = 0; b < nb; ++b){ int t = bsum[b]; bsum[b] = run; run += t; }
  }
}

__global__ void k_scan3(const int* __restrict__ tmp, const int* __restrict__ bsum,
                        int* __restrict__ rowptr, int n){
  int i = blockIdx.x*256 + threadIdx.x;
  if (i < n) rowptr[i+1] = tmp[i] + bsum[blockIdx.x];
  if (i == 0) rowptr[0] = 0;
}

// atomic-free fill: packed (col, raw_w) 8B scattered write per edge
__global__ void k_fill2(const int* __restrict__ row, const int* __restrict__ col,
                        const float* __restrict__ w, const int* __restrict__ rowptr,
                        const int* __restrict__ pos, int2* __restrict__ ecw, int e){
  int i = blockIdx.x*256 + threadIdx.x;
  if (i < e){
    int r = row[i];
    int p = rowptr[r] + pos[i];
    ecw[p] = make_int2(col[i], __float_as_int(w[i]));
  }
}

// pass1: weighted degree per node (wave-cooperative, no atomics) -> dinv
__global__ __launch_bounds__(256) void k_deg2(const int2* __restrict__ ecw,
                                              const int* __restrict__ rowptr,
                                              float* __restrict__ dinv, int n){
  int node = blockIdx.x*4 + (threadIdx.x >> 6);
  if (node >= n) return;
  int lane = threadIdx.x & 63;
  int e0 = rowptr[node], e1 = rowptr[node+1];
  float s = 0.f;
  for (int e = e0 + lane; e < e1; e += 64) s += __int_as_float(ecw[e].y);
  #pragma unroll
  for (int off = 32; off > 0; off >>= 1) s += __shfl_xor(s, off, 64);
  if (lane == 0) dinv[node] = (s > 0.f) ? rsqrtf(s) : 0.f;
}

// pass2: normalize in place: w <- -dinv[r]*w*dinv[c]
__global__ __launch_bounds__(256) void k_norm(int2* __restrict__ ecw,
                                              const int* __restrict__ rowptr,
                                              const float* __restrict__ dinv, int n){
  int node = blockIdx.x*4 + (threadIdx.x >> 6);
  if (node >= n) return;
  int lane = threadIdx.x & 63;
  int e0 = rowptr[node], e1 = rowptr[node+1];
  float dr = -dinv[node];
  for (int e = e0 + lane; e < e1; e += 64){
    int2 p = ecw[e];
    float wn = dr * __int_as_float(p.y) * dinv[p.x];
    ecw[e] = make_int2(p.x, __float_as_int(wn));
  }
}

// merged weight transpose: (nc,128,128) f32 -> [chunk][col][k] bf16, all three mats
__global__ void k_transw_all(const float* __restrict__ W1, const float* __restrict__ c1W,
                             const float* __restrict__ c2W, bf16_t* __restrict__ Wt1,
                             bf16_t* __restrict__ Wtc1, bf16_t* __restrict__ Wtc2){
  int idx = blockIdx.x*256 + threadIdx.x;   // 8*16384 total
  const float* src; bf16_t* dst; int local;
  if (idx < 2*16384)      { src = W1;  dst = Wt1;  local = idx; }
  else if (idx < 5*16384) { src = c1W; dst = Wtc1; local = idx - 2*16384; }
  else                    { src = c2W; dst = Wtc2; local = idx - 5*16384; }
  int c = local >> 14, r = (local >> 7) & 127, j = local & 127;
  dst[(c << 14) + (j << 7) + r] = (bf16_t)src[local];
}

// ---------------- GEMM: OUT(Mx128) = relu?( [A0|A1|A2] @ Wt^T + bias ) ----------------
template<bool SRCF32, int NCHUNK>
__global__ __launch_bounds__(256) void k_gemm(
    const void* __restrict__ a0, const void* __restrict__ a1, const void* __restrict__ a2,
    int astride,
    const bf16_t* __restrict__ Wt, const float* __restrict__ bias,
    bf16_t* __restrict__ out, int M, int dorelu)
{
  __shared__ bf16_t As[128][40];
  const int tid = threadIdx.x;
  const int wave = tid >> 6, lane = tid & 63;
  const int wm = wave >> 1, wn = wave & 1;
  const int l15 = lane & 15, lq = lane >> 4;
  const int blockRow = blockIdx.x * 128;

  f32x4 acc[4][4];
  #pragma unroll
  for (int a = 0; a < 4; ++a)
    #pragma unroll
    for (int b = 0; b < 4; ++b) acc[a][b] = f32x4{0.f,0.f,0.f,0.f};

  const int srow = tid >> 1;
  const int scol = (tid & 1) * 16;
  const int grow = blockRow + srow;

  #pragma unroll
  for (int chunk = 0; chunk < NCHUNK; ++chunk){
    const void* src = (chunk == 0) ? a0 : ((chunk == 1) ? a1 : a2);
    #pragma unroll
    for (int k4 = 0; k4 < 4; ++k4){
      const int kk = k4 * 32;
      {
        union { bf16_t h[16]; uint4 q[2]; } u;
        if (grow < M){
          if (SRCF32){
            const float* p = (const float*)src + (size_t)grow*astride + kk + scol;
            floatv4 vv[4];
            #pragma unroll
            for (int j = 0; j < 4; ++j) vv[j] = *(const floatv4*)(p + j*4);
            #pragma unroll
            for (int j = 0; j < 16; ++j) u.h[j] = (bf16_t)vv[j>>2][j&3];
          } else {
            const bf16_t* p = (const bf16_t*)src + (size_t)grow*astride + kk + scol;
            u.q[0] = *(const uint4*)p;
            u.q[1] = *(const uint4*)(p + 8);
          }
        } else {
          u.q[0] = make_uint4(0,0,0,0);
          u.q[1] = make_uint4(0,0,0,0);
        }
        *(uint4*)&As[srow][scol]     = u.q[0];
        *(uint4*)&As[srow][scol + 8] = u.q[1];
      }
      __syncthreads();
      bf16x8 af[4], bfr[4];
      #pragma unroll
      for (int fm = 0; fm < 4; ++fm)
        af[fm] = *(const bf16x8*)&As[wm*64 + fm*16 + l15][lq*8];
      #pragma unroll
      for (int fn = 0; fn < 4; ++fn){
        int colg = wn*64 + fn*16 + l15;
        bfr[fn] = *(const bf16x8*)&Wt[((size_t)((chunk << 7) + colg) << 7) + kk + lq*8];
      }
      #pragma unroll
      for (int fm = 0; fm < 4; ++fm)
        #pragma unroll
        for (int fn = 0; fn < 4; ++fn)
          acc[fm][fn] = __builtin_amdgcn_mfma_f32_16x16x32_bf16(af[fm], bfr[fn], acc[fm][fn], 0, 0, 0);
      __syncthreads();
    }
  }
  #pragma unroll
  for (int fm = 0; fm < 4; ++fm){
    #pragma unroll
    for (int j = 0; j < 4; ++j){
      int r = wm*64 + fm*16 + lq*4 + j;
      int growo = blockRow + r;
      if (growo < M){
        #pragma unroll
        for (int fn = 0; fn < 4; ++fn){
          int c = wn*64 + fn*16 + l15;
          float v = acc[fm][fn][j] + bias[c];
          if (dorelu) v = fmaxf(v, 0.f);
          out[((size_t)growo << 7) + c] = (bf16_t)v;
        }
      }
    }
  }
}

// ---------------- SpMM: out[i] = alpha * sum_e wn[e]*V[col[e]]  (- sub[i]) ----------------
__global__ __launch_bounds__(256) void k_spmm(
    const int* __restrict__ rowptr, const int2* __restrict__ ecw,
    const bf16_t* __restrict__ V, const bf16_t* __restrict__ sub, float alpha,
    bf16_t* __restrict__ out, int n)
{
  int node = blockIdx.x*4 + (threadIdx.x >> 6);
  if (node >= n) return;
  int lane = threadIdx.x & 63;
  int fo = lane * 2;
  int e = rowptr[node], e1 = rowptr[node+1];
  float acc0 = 0.f, acc1 = 0.f;
  for (; e + 4 <= e1; e += 4){
    int2 q0 = ecw[e], q1 = ecw[e+1], q2 = ecw[e+2], q3 = ecw[e+3];
    unsigned int p0 = *(const unsigned int*)(V + ((size_t)q0.x << 7) + fo);
    unsigned int p1 = *(const unsigned int*)(V + ((size_t)q1.x << 7) + fo);
    unsigned int p2 = *(const unsigned int*)(V + ((size_t)q2.x << 7) + fo);
    unsigned int p3 = *(const unsigned int*)(V + ((size_t)q3.x << 7) + fo);
    float w0 = __int_as_float(q0.y), w1 = __int_as_float(q1.y);
    float w2 = __int_as_float(q2.y), w3 = __int_as_float(q3.y);
    acc0 += w0 * bflo(p0); acc1 += w0 * bfhi(p0);
    acc0 += w1 * bflo(p1); acc1 += w1 * bfhi(p1);
    acc0 += w2 * bflo(p2); acc1 += w2 * bfhi(p2);
    acc0 += w3 * bflo(p3); acc1 += w3 * bfhi(p3);
  }
  for (; e < e1; ++e){
    int2 q0 = ecw[e];
    unsigned int p0 = *(const unsigned int*)(V + ((size_t)q0.x << 7) + fo);
    float w0 = __int_as_float(q0.y);
    acc0 += w0 * bflo(p0); acc1 += w0 * bfhi(p0);
  }
  float r0 = alpha * acc0, r1 = alpha * acc1;
  if (sub){
    unsigned int s = *(const unsigned int*)(sub + ((size_t)node << 7) + fo);
    r0 -= bflo(s); r1 -= bfhi(s);
  }
  union { bf16_t h[2]; unsigned int u; } o;
  o.h[0] = (bf16_t)r0; o.h[1] = (bf16_t)r1;
  *(unsigned int*)(out + ((size_t)node << 7) + fo) = o.u;
}

// ---------------- head ----------------
__global__ __launch_bounds__(256) void k_head(
    const bf16_t* __restrict__ h, const float* __restrict__ W2, const float* __restrict__ b2,
    float* __restrict__ out, int n)
{
  int node = blockIdx.x*4 + (threadIdx.x >> 6);
  if (node >= n) return;
  int lane = threadIdx.x & 63;
  unsigned int p = *(const unsigned int*)(h + ((size_t)node << 7) + lane*2);
  float h0 = bflo(p), h1 = bfhi(p);
  floatv4 w = *(const floatv4*)(W2 + lane*4);
  float p0 = h0*w[0] + h1*w[2];
  float p1 = h0*w[1] + h1*w[3];
  #pragma unroll
  for (int s = 32; s > 0; s >>= 1){
    p0 += __shfl_xor(p0, s, 64);
    p1 += __shfl_xor(p1, s, 64);
  }
  if (lane == 0){
    float l0 = p0 + b2[0], l1 = p1 + b2[1];
    float m = fmaxf(l0, l1);
    float e0 = __expf(l0 - m), e1 = __expf(l1 - m);
    float inv = 1.f / (e0 + e1);
    out[(size_t)node*2]     = e0 * inv;
    out[(size_t)node*2 + 1] = e1 * inv;
  }
}

// ---------------- launch ----------------

extern "C" void kernel_launch(void* const* d_in, const int* in_sizes, int n_in,
                              void* d_out, int out_size, void* d_ws, size_t ws_size,
                              hipStream_t stream)
{
  const float* x   = (const float*)d_in[0];
  const int*   ei  = (const int*)d_in[1];
  const float* ew  = (const float*)d_in[2];
  const float* W1  = (const float*)d_in[3];
  const float* b1  = (const float*)d_in[4];
  const float* c1W = (const float*)d_in[5];
  const float* c1b = (const float*)d_in[6];
  const float* c2W = (const float*)d_in[7];
  const float* c2b = (const float*)d_in[8];
  const float* W2  = (const float*)d_in[9];
  const float* b2  = (const float*)d_in[10];
  float* out = (float*)d_out;

  const int n = NN, e = NE;
  const int* row = ei;
  const int* col = ei + e;

  char* ws = (char*)d_ws;
  size_t off = 0;
  auto carve = [&](size_t bytes)->void*{
    void* p = ws + off;
    off += (bytes + 255) & ~(size_t)255;
    return p;
  };
  bf16_t* A    = (bf16_t*)carve((size_t)n*128*2);
  bf16_t* B    = (bf16_t*)carve((size_t)n*128*2);
  bf16_t* C    = (bf16_t*)carve((size_t)n*128*2);
  bf16_t* D    = (bf16_t*)carve((size_t)n*128*2);
  float*  dinv = (float*)carve((size_t)n*4);
  int*    cnt  = (int*)carve((size_t)n*4);
  int*    rowptr = (int*)carve((size_t)(n+1)*4);
  int*    bsum = (int*)carve(512*4);
  int2*   ecw  = (int2*)carve((size_t)e*8);
  bf16_t* Wt1  = (bf16_t*)carve(2*128*128*2);
  bf16_t* Wtc1 = (bf16_t*)carve(3*128*128*2);
  bf16_t* Wtc2 = (bf16_t*)carve(3*128*128*2);
  // aliases (lifetimes end before their hosts are first written):
  int* pos = (int*)B;     // used k_count..k_fill2; B first written by spmm later
  int* tmp = (int*)C;     // used scan1..scan3; C first written by spmm later
  (void)ws_size; (void)in_sizes; (void)n_in; (void)out_size;

  const int NB_N = (n + 255)/256;   // 391
  const int NB_E = (e + 255)/256;   // 6250
  const int NB_G = (n + 127)/128;   // 782
  const int NB_W = (n + 3)/4;       // 25000

  hipMemsetAsync(cnt, 0, (size_t)n*4, stream);
  k_count<<<NB_E,256,0,stream>>>(row, cnt, pos, e);
  k_scan1<<<NB_N,256,0,stream>>>(cnt, tmp, bsum, n);
  k_scan2<<<1,64,0,stream>>>(bsum, NB_N);
  k_scan3<<<NB_N,256,0,stream>>>(tmp, bsum, rowptr, n);
  k_fill2<<<NB_E,256,0,stream>>>(row, col, ew, rowptr, pos, ecw, e);
  k_deg2<<<NB_W,256,0,stream>>>(ecw, rowptr, dinv, n);
  k_norm<<<NB_W,256,0,stream>>>(ecw, rowptr, dinv, n);
  k_transw_all<<<(8*16384+255)/256,256,0,stream>>>(W1, c1W, c2W, Wt1, Wtc1, Wtc2);

  // h0 = relu(x @ W1 + b1)        -> A
  k_gemm<true,2><<<NB_G,256,0,stream>>>(x, x+128, nullptr, 256, Wt1, b1, A, n, 1);
  // conv1: Tx1 = Lx(h0)           -> B
  k_spmm<<<NB_W,256,0,stream>>>(rowptr, ecw, A, nullptr, 1.f, B, n);
  //        Tx2 = 2*Lx(Tx1) - h0   -> C
  k_spmm<<<NB_W,256,0,stream>>>(rowptr, ecw, B, A, 2.f, C, n);
  //        h1 = relu([A|B|C] @ Wc1 + b) -> D
  k_gemm<false,3><<<NB_G,256,0,stream>>>(A, B, C, 128, Wtc1, c1b, D, n, 1);
  // conv2
  k_spmm<<<NB_W,256,0,stream>>>(rowptr, ecw, D, nullptr, 1.f, B, n);
  k_spmm<<<NB_W,256,0,stream>>>(rowptr, ecw, B, D, 2.f, C, n);
  k_gemm<false,3><<<NB_G,256,0,stream>>>(D, B, C, 128, Wtc2, c2b, A, n, 1);
  // head
  k_head<<<NB_W,256,0,stream>>>(A, W2, b2, out, n);
}

// Round 3
// 580.931 us; speedup vs baseline: 1.4198x; 1.0553x over previous
//
#include <hip/hip_runtime.h>
#include <hip/hip_bf16.h>
#include <stdint.h>

typedef __bf16 bf16_t;
typedef __bf16 bf16x8 __attribute__((ext_vector_type(8)));
typedef float f32x4 __attribute__((ext_vector_type(4)));
typedef float floatv4 __attribute__((ext_vector_type(4)));

static __device__ __forceinline__ float bflo(unsigned int p){ return __uint_as_float(p << 16); }
static __device__ __forceinline__ float bfhi(unsigned int p){ return __uint_as_float(p & 0xffff0000u); }
static __device__ __forceinline__ unsigned int pack2(float lo, float hi){
  union { bf16_t h[2]; unsigned int u; } o;
  o.h[0] = (bf16_t)lo; o.h[1] = (bf16_t)hi;
  return o.u;
}

constexpr int NN = 100000;
constexpr int NE = 1600000;

// ---------------- CSR build ----------------
__global__ void k_count(const int* __restrict__ row, int* __restrict__ cnt,
                        int* __restrict__ pos, int e){
  int i = blockIdx.x*256 + threadIdx.x;
  if (i < e) pos[i] = atomicAdd(&cnt[row[i]], 1);
}

__global__ void k_scan1(const int* __restrict__ cnt, int* __restrict__ tmp,
                        int* __restrict__ bsum, int n){
  __shared__ int s[256];
  int i = blockIdx.x*256 + threadIdx.x;
  s[threadIdx.x] = (i < n) ? cnt[i] : 0;
  __syncthreads();
  for (int off = 1; off < 256; off <<= 1){
    int t = (threadIdx.x >= off) ? s[threadIdx.x - off] : 0;
    __syncthreads();
    s[threadIdx.x] += t;
    __syncthreads();
  }
  if (i < n) tmp[i] = s[threadIdx.x];
  if (threadIdx.x == 255) bsum[blockIdx.x] = s[255];
}

__global__ void k_scan2(int* bsum, int nb){
  if (threadIdx.x == 0 && blockIdx.x == 0){
    int run = 0;
    for (int b = 0; b < nb; ++b){ int t = bsum[b]; bsum[b] = run; run += t; }
  }
}

__global__ void k_scan3(const int* __restrict__ tmp, const int* __restrict__ bsum,
                        int* __restrict__ rowptr, int n){
  int i = blockIdx.x*256 + threadIdx.x;
  if (i < n) rowptr[i+1] = tmp[i] + bsum[blockIdx.x];
  if (i == 0) rowptr[0] = 0;
}

__global__ void k_fill2(const int* __restrict__ row, const int* __restrict__ col,
                        const float* __restrict__ w, const int* __restrict__ rowptr,
                        const int* __restrict__ pos, int2* __restrict__ ecw, int e){
  int i = blockIdx.x*256 + threadIdx.x;
  if (i < e){
    int r = row[i];
    int p = rowptr[r] + pos[i];
    ecw[p] = make_int2(col[i], __float_as_int(w[i]));
  }
}

__global__ __launch_bounds__(256) void k_deg2(const int2* __restrict__ ecw,
                                              const int* __restrict__ rowptr,
                                              float* __restrict__ dinv, int n){
  int node = blockIdx.x*4 + (threadIdx.x >> 6);
  if (node >= n) return;
  int lane = threadIdx.x & 63;
  int e0 = rowptr[node], e1 = rowptr[node+1];
  float s = 0.f;
  for (int e = e0 + lane; e < e1; e += 64) s += __int_as_float(ecw[e].y);
  #pragma unroll
  for (int off = 32; off > 0; off >>= 1) s += __shfl_xor(s, off, 64);
  if (lane == 0) dinv[node] = (s > 0.f) ? rsqrtf(s) : 0.f;
}

__global__ __launch_bounds__(256) void k_norm(int2* __restrict__ ecw,
                                              const int* __restrict__ rowptr,
                                              const float* __restrict__ dinv, int n){
  int node = blockIdx.x*4 + (threadIdx.x >> 6);
  if (node >= n) return;
  int lane = threadIdx.x & 63;
  int e0 = rowptr[node], e1 = rowptr[node+1];
  float dr = -dinv[node];
  for (int e = e0 + lane; e < e1; e += 64){
    int2 p = ecw[e];
    float wn = dr * __int_as_float(p.y) * dinv[p.x];
    ecw[e] = make_int2(p.x, __float_as_int(wn));
  }
}

__global__ void k_transw_all(const float* __restrict__ W1, const float* __restrict__ c1W,
                             const float* __restrict__ c2W, bf16_t* __restrict__ Wt1,
                             bf16_t* __restrict__ Wtc1, bf16_t* __restrict__ Wtc2){
  int idx = blockIdx.x*256 + threadIdx.x;   // 8*16384 total
  const float* src; bf16_t* dst; int local;
  if (idx < 2*16384)      { src = W1;  dst = Wt1;  local = idx; }
  else if (idx < 5*16384) { src = c1W; dst = Wtc1; local = idx - 2*16384; }
  else                    { src = c2W; dst = Wtc2; local = idx - 5*16384; }
  int c = local >> 14, r = (local >> 7) & 127, j = local & 127;
  dst[(c << 14) + (j << 7) + r] = (bf16_t)src[local];
}

// ---------------- GEMM: OUT(Mx128) = relu?( [A0|A1|A2] @ Wt^T + bias ) ----------------
template<bool SRCF32, int NCHUNK>
__global__ __launch_bounds__(256) void k_gemm(
    const void* __restrict__ a0, const void* __restrict__ a1, const void* __restrict__ a2,
    int astride,
    const bf16_t* __restrict__ Wt, const float* __restrict__ bias,
    bf16_t* __restrict__ out, int M, int dorelu)
{
  __shared__ bf16_t As[128][40];
  const int tid = threadIdx.x;
  const int wave = tid >> 6, lane = tid & 63;
  const int wm = wave >> 1, wn = wave & 1;
  const int l15 = lane & 15, lq = lane >> 4;
  const int blockRow = blockIdx.x * 128;

  f32x4 acc[4][4];
  #pragma unroll
  for (int a = 0; a < 4; ++a)
    #pragma unroll
    for (int b = 0; b < 4; ++b) acc[a][b] = f32x4{0.f,0.f,0.f,0.f};

  const int srow = tid >> 1;
  const int scol = (tid & 1) * 16;
  const int grow = blockRow + srow;

  #pragma unroll
  for (int chunk = 0; chunk < NCHUNK; ++chunk){
    const void* src = (chunk == 0) ? a0 : ((chunk == 1) ? a1 : a2);
    #pragma unroll
    for (int k4 = 0; k4 < 4; ++k4){
      const int kk = k4 * 32;
      {
        union { bf16_t h[16]; uint4 q[2]; } u;
        if (grow < M){
          if (SRCF32){
            const float* p = (const float*)src + (size_t)grow*astride + kk + scol;
            floatv4 vv[4];
            #pragma unroll
            for (int j = 0; j < 4; ++j) vv[j] = *(const floatv4*)(p + j*4);
            #pragma unroll
            for (int j = 0; j < 16; ++j) u.h[j] = (bf16_t)vv[j>>2][j&3];
          } else {
            const bf16_t* p = (const bf16_t*)src + (size_t)grow*astride + kk + scol;
            u.q[0] = *(const uint4*)p;
            u.q[1] = *(const uint4*)(p + 8);
          }
        } else {
          u.q[0] = make_uint4(0,0,0,0);
          u.q[1] = make_uint4(0,0,0,0);
        }
        *(uint4*)&As[srow][scol]     = u.q[0];
        *(uint4*)&As[srow][scol + 8] = u.q[1];
      }
      __syncthreads();
      bf16x8 af[4], bfr[4];
      #pragma unroll
      for (int fm = 0; fm < 4; ++fm)
        af[fm] = *(const bf16x8*)&As[wm*64 + fm*16 + l15][lq*8];
      #pragma unroll
      for (int fn = 0; fn < 4; ++fn){
        int colg = wn*64 + fn*16 + l15;
        bfr[fn] = *(const bf16x8*)&Wt[((size_t)((chunk << 7) + colg) << 7) + kk + lq*8];
      }
      #pragma unroll
      for (int fm = 0; fm < 4; ++fm)
        #pragma unroll
        for (int fn = 0; fn < 4; ++fn)
          acc[fm][fn] = __builtin_amdgcn_mfma_f32_16x16x32_bf16(af[fm], bfr[fn], acc[fm][fn], 0, 0, 0);
      __syncthreads();
    }
  }
  #pragma unroll
  for (int fm = 0; fm < 4; ++fm){
    #pragma unroll
    for (int j = 0; j < 4; ++j){
      int r = wm*64 + fm*16 + lq*4 + j;
      int growo = blockRow + r;
      if (growo < M){
        #pragma unroll
        for (int fn = 0; fn < 4; ++fn){
          int c = wn*64 + fn*16 + l15;
          float v = acc[fm][fn][j] + bias[c];
          if (dorelu) v = fmaxf(v, 0.f);
          out[((size_t)growo << 7) + c] = (bf16_t)v;
        }
      }
    }
  }
}

// ---------------- SpMM v2: 4 nodes/wave, 16 lanes/node, 16B/lane gathers ----------------
// out[i] = alpha * sum_e wn[e]*V[col[e]]  (- sub[i])
static __device__ __forceinline__ void accum8(float* a, uint4 p, float w){
  a[0] += w*bflo(p.x); a[1] += w*bfhi(p.x);
  a[2] += w*bflo(p.y); a[3] += w*bfhi(p.y);
  a[4] += w*bflo(p.z); a[5] += w*bfhi(p.z);
  a[6] += w*bflo(p.w); a[7] += w*bfhi(p.w);
}

__global__ __launch_bounds__(256) void k_spmm4(
    const int* __restrict__ rowptr, const int2* __restrict__ ecw,
    const bf16_t* __restrict__ V, const bf16_t* __restrict__ sub, float alpha,
    bf16_t* __restrict__ out, int n)
{
  const int lane = threadIdx.x & 63;
  const int wave = threadIdx.x >> 6;
  const int g = lane >> 4;           // node-group within wave
  const int s = lane & 15;           // sublane: 8 features (16B) of the row
  const int node = blockIdx.x*16 + wave*4 + g;
  if (node >= n) return;

  int e = rowptr[node];
  const int e1 = rowptr[node+1];
  const char* Vb = (const char*)V;
  const int fb = s << 4;             // byte offset within 256B row

  float acc[8] = {0.f,0.f,0.f,0.f,0.f,0.f,0.f,0.f};

  for (; e + 4 <= e1; e += 4){
    int2 q0 = ecw[e], q1 = ecw[e+1], q2 = ecw[e+2], q3 = ecw[e+3];
    uint4 p0 = *(const uint4*)(Vb + (((size_t)(unsigned)q0.x) << 8) + fb);
    uint4 p1 = *(const uint4*)(Vb + (((size_t)(unsigned)q1.x) << 8) + fb);
    uint4 p2 = *(const uint4*)(Vb + (((size_t)(unsigned)q2.x) << 8) + fb);
    uint4 p3 = *(const uint4*)(Vb + (((size_t)(unsigned)q3.x) << 8) + fb);
    accum8(acc, p0, __int_as_float(q0.y));
    accum8(acc, p1, __int_as_float(q1.y));
    accum8(acc, p2, __int_as_float(q2.y));
    accum8(acc, p3, __int_as_float(q3.y));
  }
  for (; e < e1; ++e){
    int2 q = ecw[e];
    uint4 p = *(const uint4*)(Vb + (((size_t)(unsigned)q.x) << 8) + fb);
    accum8(acc, p, __int_as_float(q.y));
  }

  uint4 o;
  if (sub){
    uint4 sv = *(const uint4*)((const char*)sub + (((size_t)node) << 8) + fb);
    o.x = pack2(alpha*acc[0] - bflo(sv.x), alpha*acc[1] - bfhi(sv.x));
    o.y = pack2(alpha*acc[2] - bflo(sv.y), alpha*acc[3] - bfhi(sv.y));
    o.z = pack2(alpha*acc[4] - bflo(sv.z), alpha*acc[5] - bfhi(sv.z));
    o.w = pack2(alpha*acc[6] - bflo(sv.w), alpha*acc[7] - bfhi(sv.w));
  } else {
    o.x = pack2(alpha*acc[0], alpha*acc[1]);
    o.y = pack2(alpha*acc[2], alpha*acc[3]);
    o.z = pack2(alpha*acc[4], alpha*acc[5]);
    o.w = pack2(alpha*acc[6], alpha*acc[7]);
  }
  *(uint4*)((char*)out + (((size_t)node) << 8) + fb) = o;
}

// ---------------- head ----------------
__global__ __launch_bounds__(256) void k_head(
    const bf16_t* __restrict__ h, const float* __restrict__ W2, const float* __restrict__ b2,
    float* __restrict__ out, int n)
{
  int node = blockIdx.x*4 + (threadIdx.x >> 6);
  if (node >= n) return;
  int lane = threadIdx.x & 63;
  unsigned int p = *(const unsigned int*)(h + ((size_t)node << 7) + lane*2);
  float h0 = bflo(p), h1 = bfhi(p);
  floatv4 w = *(const floatv4*)(W2 + lane*4);
  float p0 = h0*w[0] + h1*w[2];
  float p1 = h0*w[1] + h1*w[3];
  #pragma unroll
  for (int s = 32; s > 0; s >>= 1){
    p0 += __shfl_xor(p0, s, 64);
    p1 += __shfl_xor(p1, s, 64);
  }
  if (lane == 0){
    float l0 = p0 + b2[0], l1 = p1 + b2[1];
    float m = fmaxf(l0, l1);
    float e0 = __expf(l0 - m), e1 = __expf(l1 - m);
    float inv = 1.f / (e0 + e1);
    out[(size_t)node*2]     = e0 * inv;
    out[(size_t)node*2 + 1] = e1 * inv;
  }
}

// ---------------- launch ----------------

extern "C" void kernel_launch(void* const* d_in, const int* in_sizes, int n_in,
                              void* d_out, int out_size, void* d_ws, size_t ws_size,
                              hipStream_t stream)
{
  const float* x   = (const float*)d_in[0];
  const int*   ei  = (const int*)d_in[1];
  const float* ew  = (const float*)d_in[2];
  const float* W1  = (const float*)d_in[3];
  const float* b1  = (const float*)d_in[4];
  const float* c1W = (const float*)d_in[5];
  const float* c1b = (const float*)d_in[6];
  const float* c2W = (const float*)d_in[7];
  const float* c2b = (const float*)d_in[8];
  const float* W2  = (const float*)d_in[9];
  const float* b2  = (const float*)d_in[10];
  float* out = (float*)d_out;

  const int n = NN, e = NE;
  const int* row = ei;
  const int* col = ei + e;

  char* ws = (char*)d_ws;
  size_t off = 0;
  auto carve = [&](size_t bytes)->void*{
    void* p = ws + off;
    off += (bytes + 255) & ~(size_t)255;
    return p;
  };
  bf16_t* A    = (bf16_t*)carve((size_t)n*128*2);
  bf16_t* B    = (bf16_t*)carve((size_t)n*128*2);
  bf16_t* C    = (bf16_t*)carve((size_t)n*128*2);
  bf16_t* D    = (bf16_t*)carve((size_t)n*128*2);
  float*  dinv = (float*)carve((size_t)n*4);
  int*    cnt  = (int*)carve((size_t)n*4);
  int*    rowptr = (int*)carve((size_t)(n+1)*4);
  int*    bsum = (int*)carve(512*4);
  int2*   ecw  = (int2*)carve((size_t)e*8);
  bf16_t* Wt1  = (bf16_t*)carve(2*128*128*2);
  bf16_t* Wtc1 = (bf16_t*)carve(3*128*128*2);
  bf16_t* Wtc2 = (bf16_t*)carve(3*128*128*2);
  // aliases (lifetimes end before their hosts are first written):
  int* pos = (int*)B;     // used k_count..k_fill2; B first written by spmm later
  int* tmp = (int*)C;     // used scan1..scan3; C first written by spmm later
  (void)ws_size; (void)in_sizes; (void)n_in; (void)out_size;

  const int NB_N = (n + 255)/256;   // 391
  const int NB_E = (e + 255)/256;   // 6250
  const int NB_G = (n + 127)/128;   // 782
  const int NB_W = (n + 3)/4;       // 25000
  const int NB_S = (n + 15)/16;     // 6250

  hipMemsetAsync(cnt, 0, (size_t)n*4, stream);
  k_count<<<NB_E,256,0,stream>>>(row, cnt, pos, e);
  k_scan1<<<NB_N,256,0,stream>>>(cnt, tmp, bsum, n);
  k_scan2<<<1,64,0,stream>>>(bsum, NB_N);
  k_scan3<<<NB_N,256,0,stream>>>(tmp, bsum, rowptr, n);
  k_fill2<<<NB_E,256,0,stream>>>(row, col, ew, rowptr, pos, ecw, e);
  k_deg2<<<NB_W,256,0,stream>>>(ecw, rowptr, dinv, n);
  k_norm<<<NB_W,256,0,stream>>>(ecw, rowptr, dinv, n);
  k_transw_all<<<(8*16384+255)/256,256,0,stream>>>(W1, c1W, c2W, Wt1, Wtc1, Wtc2);

  // h0 = relu(x @ W1 + b1)        -> A
  k_gemm<true,2><<<NB_G,256,0,stream>>>(x, x+128, nullptr, 256, Wt1, b1, A, n, 1);
  // conv1: Tx1 = Lx(h0)           -> B
  k_spmm4<<<NB_S,256,0,stream>>>(rowptr, ecw, A, nullptr, 1.f, B, n);
  //        Tx2 = 2*Lx(Tx1) - h0   -> C
  k_spmm4<<<NB_S,256,0,stream>>>(rowptr, ecw, B, A, 2.f, C, n);
  //        h1 = relu([A|B|C] @ Wc1 + b) -> D
  k_gemm<false,3><<<NB_G,256,0,stream>>>(A, B, C, 128, Wtc1, c1b, D, n, 1);
  // conv2
  k_spmm4<<<NB_S,256,0,stream>>>(rowptr, ecw, D, nullptr, 1.f, B, n);
  k_spmm4<<<NB_S,256,0,stream>>>(rowptr, ecw, B, D, 2.f, C, n);
  k_gemm<false,3><<<NB_G,256,0,stream>>>(D, B, C, 128, Wtc2, c2b, A, n, 1);
  // head
  k_head<<<NB_W,256,0,stream>>>(A, W2, b2, out, n);
}